// Round 2
// baseline (32.856 us; speedup 1.0000x reference)
//
#include <hip/hip_runtime.h>

// Problem constants (from reference): feat (32, 64, 112, 112) fp32
#define BB 32
#define CC 64
#define HH 112
#define WW 112
#define HW (HH * WW)          // 12544
#define KS 14
#define HP (HH - KS + 1)      // 99
#define WP (WW - KS + 1)      // 99

// Kernel 1: s2[b,h,w] = (sum_c feat[b,c,h,w])^2, float4-vectorized over (h,w).
// Reads the entire 102.8 MB input once -> HBM-bound, everything else is tiny.
__global__ __launch_bounds__(256) void chan_sum_sq(const float* __restrict__ feat,
                                                   float* __restrict__ s2) {
    const int n4 = BB * (HW / 4);
    int idx4 = blockIdx.x * blockDim.x + threadIdx.x;
    if (idx4 >= n4) return;
    int b = idx4 / (HW / 4);
    int r = idx4 % (HW / 4);
    const float4* base =
        reinterpret_cast<const float4*>(feat) + (size_t)b * CC * (HW / 4) + r;
    float4 acc = make_float4(0.f, 0.f, 0.f, 0.f);
#pragma unroll 8
    for (int c = 0; c < CC; ++c) {
        float4 v = base[(size_t)c * (HW / 4)];
        acc.x += v.x; acc.y += v.y; acc.z += v.z; acc.w += v.w;
    }
    float4 o;
    o.x = acc.x * acc.x;
    o.y = acc.y * acc.y;
    o.z = acc.z * acc.z;
    o.w = acc.w * acc.w;
    reinterpret_cast<float4*>(s2)[idx4] = o;
}

// Kernel 2 (fused): per-image separable 14x14 window mean + 8-neighbor sim.
// One block per batch image; hbuf/pbuf staged in LDS (44.3 KB + 39.2 KB).
__global__ __launch_bounds__(1024) void pool_sim_fused(const float* __restrict__ s2,
                                                       float* __restrict__ out) {
    __shared__ float hbuf[HH * WP];  // horizontal 14-tap sums
    __shared__ float pbuf[HP * WP];  // pooled (vertical sums * 1/196)

    const int b = blockIdx.x;
    const int tid = threadIdx.x;
    const int nt = blockDim.x;
    const float* img = s2 + (size_t)b * HW;

    // Horizontal pass: hbuf[h][wp] = sum_k img[h][wp+k]; reads hit L1/L2.
    for (int i = tid; i < HH * WP; i += nt) {
        int h = i / WP;
        int wp = i - h * WP;
        const float* row = img + h * WW + wp;
        float s = 0.f;
#pragma unroll
        for (int k = 0; k < KS; ++k) s += row[k];
        hbuf[i] = s;
    }
    __syncthreads();

    // Vertical pass: pbuf[hp][wp] = (sum_k hbuf[hp+k][wp]) / 196
    for (int i = tid; i < HP * WP; i += nt) {
        int hp = i / WP;
        int wp = i - hp * WP;
        const float* col = hbuf + hp * WP + wp;
        float s = 0.f;
#pragma unroll
        for (int k = 0; k < KS; ++k) s += col[k * WP];
        pbuf[i] = s * (1.f / (float)(KS * KS));
    }
    __syncthreads();

    // Sim pass: out = C^2 * center * (zero-padded 8-neighbor sum)
    float* ob = out + (size_t)b * HP * WP;
    for (int i = tid; i < HP * WP; i += nt) {
        int hp = i / WP;
        int wp = i - hp * WP;
        float center = pbuf[i];
        float ns = 0.f;
#pragma unroll
        for (int dy = -1; dy <= 1; ++dy) {
#pragma unroll
            for (int dx = -1; dx <= 1; ++dx) {
                if (dy == 0 && dx == 0) continue;
                int y = hp + dy, x = wp + dx;
                if (y >= 0 && y < HP && x >= 0 && x < WP) {
                    ns += pbuf[y * WP + x];
                }
            }
        }
        ob[i] = (float)(CC * CC) * center * ns;
    }
}

extern "C" void kernel_launch(void* const* d_in, const int* in_sizes, int n_in,
                              void* d_out, int out_size, void* d_ws, size_t ws_size,
                              hipStream_t stream) {
    const float* feat = (const float*)d_in[0];
    float* out = (float*)d_out;
    float* s2 = (float*)d_ws;  // BB*HW = 401,408 floats = 1.6 MB

    {
        int n4 = BB * (HW / 4);
        int blk = 256;
        chan_sum_sq<<<(n4 + blk - 1) / blk, blk, 0, stream>>>(feat, s2);
    }
    pool_sim_fused<<<BB, 1024, 0, stream>>>(s2, out);
}

// Round 3
// 27.399 us; speedup vs baseline: 1.1992x; 1.1992x over previous
//
#include <hip/hip_runtime.h>

// Problem constants (from reference): feat (32, 64, 112, 112) fp32
#define BB 32
#define CC 64
#define HH 112
#define WW 112
#define HW (HH * WW)          // 12544
#define KS 14
#define HP (HH - KS + 1)      // 99
#define WP (WW - KS + 1)      // 99

#define BR 11                 // pooled rows per band
#define NB 9                  // 9 * 11 = 99 = HP exactly

// Kernel 1: s2[b,h,w] = (sum_c feat[b,c,h,w])^2, float4-vectorized over (h,w).
// Reads the entire 102.8 MB input once -> HBM-bound floor ~15 us.
__global__ __launch_bounds__(256) void chan_sum_sq(const float* __restrict__ feat,
                                                   float* __restrict__ s2) {
    const int n4 = BB * (HW / 4);
    int idx4 = blockIdx.x * blockDim.x + threadIdx.x;
    if (idx4 >= n4) return;
    int b = idx4 / (HW / 4);
    int r = idx4 % (HW / 4);
    const float4* base =
        reinterpret_cast<const float4*>(feat) + (size_t)b * CC * (HW / 4) + r;
    float4 acc = make_float4(0.f, 0.f, 0.f, 0.f);
#pragma unroll 16
    for (int c = 0; c < CC; ++c) {
        float4 v = base[(size_t)c * (HW / 4)];
        acc.x += v.x; acc.y += v.y; acc.z += v.z; acc.w += v.w;
    }
    float4 o;
    o.x = acc.x * acc.x;
    o.y = acc.y * acc.y;
    o.z = acc.z * acc.z;
    o.w = acc.w * acc.w;
    reinterpret_cast<float4*>(s2)[idx4] = o;
}

// Kernel 2: band-tiled fused pooling + sim. Each block: one image, one 11-row
// band of output, with a 1-row pooled halo recomputed locally (no inter-block
// dependency). LDS 15.4 KB -> high occupancy; 288 blocks spread chip-wide.
__global__ __launch_bounds__(256) void pool_sim_band(const float* __restrict__ s2,
                                                     float* __restrict__ out) {
    __shared__ float hbuf[(BR + 2 + KS - 1) * WP];  // up to 26 rows of h-sums
    __shared__ float pbuf[(BR + 2) * WP];           // up to 13 rows of pooled

    const int b = blockIdx.y;
    const int band = blockIdx.x;
    const int r0 = band * BR;
    const int rend = min(r0 + BR, HP);
    const int pstart = max(r0 - 1, 0);
    const int pend = min(r0 + BR + 1, HP);
    const int pcount = pend - pstart;
    const int hcount = pcount + KS - 1;
    const int tid = threadIdx.x;
    const float* img = s2 + (size_t)b * HW;

    // Horizontal 14-tap sums for rows [pstart, pstart+hcount)
    for (int i = tid; i < hcount * WP; i += 256) {
        int hr = i / WP;
        int wp = i - hr * WP;
        const float* row = img + (pstart + hr) * WW + wp;
        float s = 0.f;
#pragma unroll
        for (int k = 0; k < KS; ++k) s += row[k];
        hbuf[i] = s;
    }
    __syncthreads();

    // Vertical 14-tap sums * 1/196 for pooled rows [pstart, pend)
    for (int i = tid; i < pcount * WP; i += 256) {
        int pr = i / WP;
        int wp = i - pr * WP;
        const float* col = hbuf + pr * WP + wp;
        float s = 0.f;
#pragma unroll
        for (int k = 0; k < KS; ++k) s += col[k * WP];
        pbuf[i] = s * (1.f / (float)(KS * KS));
    }
    __syncthreads();

    // Sim: out = C^2 * center * (zero-padded 8-neighbor sum), rows [r0, rend)
    float* ob = out + (size_t)b * HP * WP;
    for (int i = tid; i < (rend - r0) * WP; i += 256) {
        int rr = i / WP;
        int wp = i - rr * WP;
        int hp = r0 + rr;
        float center = pbuf[(hp - pstart) * WP + wp];
        float ns = 0.f;
#pragma unroll
        for (int dy = -1; dy <= 1; ++dy) {
#pragma unroll
            for (int dx = -1; dx <= 1; ++dx) {
                if (dy == 0 && dx == 0) continue;
                int y = hp + dy, x = wp + dx;
                if (y >= 0 && y < HP && x >= 0 && x < WP) {
                    ns += pbuf[(y - pstart) * WP + x];
                }
            }
        }
        ob[hp * WP + wp] = (float)(CC * CC) * center * ns;
    }
}

extern "C" void kernel_launch(void* const* d_in, const int* in_sizes, int n_in,
                              void* d_out, int out_size, void* d_ws, size_t ws_size,
                              hipStream_t stream) {
    const float* feat = (const float*)d_in[0];
    float* out = (float*)d_out;
    float* s2 = (float*)d_ws;  // BB*HW = 401,408 floats = 1.6 MB

    {
        int n4 = BB * (HW / 4);
        int blk = 256;
        chan_sum_sq<<<(n4 + blk - 1) / blk, blk, 0, stream>>>(feat, s2);
    }
    {
        dim3 grid(NB, BB);
        pool_sim_band<<<grid, 256, 0, stream>>>(s2, out);
    }
}